// Round 21
// baseline (304.382 us; speedup 1.0000x reference)
//
#include <hip/hip_runtime.h>

// MyConv2D: N=32, Cin=128, H=W=56, Cout=256, K=3, stride=1, pad=1, fp32.
// R21: last structural axis — 64x128 WAVE TILE at relaxed occupancy.
// acc=128 VGPR (~220 total) fits 3 waves/SIMD (12 waves/CU); LDS reads and
// staged writes drop 25% vs R16/R20 (4 waves x (64+128) rows per 128x256
// output vs 8 x 128). Tile 128(oc)x256(pix), 4 waves, BK=64, 18 K-tiles,
// R16's proven 2-barrier loop, 48KB single-buffer LDS, fused prep (R20).
// launch_bounds(256,3): cap 682 regs — no forced-spill risk (R7/R17 lesson).

typedef unsigned short u16;
typedef _Float16 f16x8 __attribute__((ext_vector_type(8)));
typedef float f32x4 __attribute__((ext_vector_type(4)));

#define CIN    128
#define COUT   256
#define HW     56
#define NPIX   3136        // 56*56
#define TOTPIX 100352      // 32*3136
#define NKT    18          // K-tiles of 64 ic: 9 taps * 2 ic-halves

#define WAITVM0 asm volatile("s_waitcnt vmcnt(0)" ::: "memory")
#define BARRIER asm volatile("s_barrier" ::: "memory")

__device__ __forceinline__ void gload16(const void* g, void* l) {
  __builtin_amdgcn_global_load_lds(
      (const __attribute__((address_space(1))) void*)g,
      (__attribute__((address_space(3))) void*)l, 16, 0, 0);
}

__device__ __forceinline__ u16 f2h(float f) {
  _Float16 h = (_Float16)f;
  return __builtin_bit_cast(u16, h);
}

// ---- fused prep (unchanged from R20): blocks 0..2047 = x -> xt
// [n][g=ic/8][pix][8ic]; blocks 2048..3199 = W -> Wt [t][octile][k8][ocl]
// granules (+ zero-page init).
__global__ void prep(const float* __restrict__ x, const float* __restrict__ W,
                     u16* __restrict__ xt, u16* __restrict__ Wt,
                     u16* __restrict__ zp) {
  int b = blockIdx.x;
  if (b < 2048) {                             // ---- prep_x part
    int n = b >> 6, g = (b >> 2) & 15, c = b & 3;
    const float* xs = x + ((size_t)(n * 16 + g) * 8) * NPIX;
    u16* xd = xt + ((size_t)(n * 16 + g) * NPIX) * 8;
    #pragma unroll
    for (int i = 0; i < 4; ++i) {
      int off = i * 256 + (int)threadIdx.x;   // 784 = 3*256 + 16
      if (off < 784) {
        int pix = c * 784 + off;
        unsigned q0, q1, q2, q3;
        q0 = (unsigned)f2h(xs[(size_t)0 * NPIX + pix]) |
             ((unsigned)f2h(xs[(size_t)1 * NPIX + pix]) << 16);
        q1 = (unsigned)f2h(xs[(size_t)2 * NPIX + pix]) |
             ((unsigned)f2h(xs[(size_t)3 * NPIX + pix]) << 16);
        q2 = (unsigned)f2h(xs[(size_t)4 * NPIX + pix]) |
             ((unsigned)f2h(xs[(size_t)5 * NPIX + pix]) << 16);
        q3 = (unsigned)f2h(xs[(size_t)6 * NPIX + pix]) |
             ((unsigned)f2h(xs[(size_t)7 * NPIX + pix]) << 16);
        uint4 v; v.x = q0; v.y = q1; v.z = q2; v.w = q3;
        *(uint4*)(xd + (size_t)pix * 8) = v;
      }
    }
  } else {                                    // ---- prep_w part
    int e = (b - 2048) * 256 + threadIdx.x;   // 1152 * 256 = 294912
    if (b == 2048 && threadIdx.x < 128) zp[threadIdx.x] = 0;
    int j   = e & 7;
    int ocl = (e >> 3) & 127;
    int k8  = (e >> 10) & 7;
    int o   = (e >> 13) & 1;
    int t   = e >> 14;                        // 0..17
    int oc = o * 128 + ocl;
    int ic = (t & 1) * 64 + k8 * 8 + j;
    Wt[e] = f2h(W[(oc * CIN + ic) * 9 + (t >> 1)]);
  }
}

__global__ __launch_bounds__(256, 3) void conv_mfma(
    const u16* __restrict__ Wt, const u16* __restrict__ xt,
    const float* __restrict__ bias, float* __restrict__ out,
    const u16* __restrict__ zp) {
  // 48KB: A [k8 8][ocl 128][8] at 0 (16KB) | B [k8 8][pixl 256][8] at 8192.
  __shared__ __align__(16) u16 lds[24576];

  int tid  = threadIdx.x;                     // 0..255
  int lane = tid & 63;
  int wv   = tid >> 6;                        // 0..3
  int bid  = blockIdx.x;                      // 0..783
  int wgid = (bid & 7) * 98 + (bid >> 3);     // XCD swizzle (784 = 8*98)
  int octile = wgid & 1;                      // same-XCD pair shares B panel
  int ptile  = wgid >> 1;                     // 0..391

  int wm = wv >> 1, wn = wv & 1;              // per-wave 64(oc) x 128(pix)
  int l15 = lane & 15, lg = lane >> 4;

  // B staging: thread owns pixel spix = tid, stages all 8 k8 granules.
  int spix = tid;
  int p = ptile * 256 + spix;
  int sn = p / NPIX, sr = p % NPIX, sy = sr / HW, sx = sr % HW;
  const char* xtb = (const char*)xt;
  const char* zpc = (const char*)zp;
  // A staging: granules linear, 4/thread: (k8*128+ocl) = tid + i*256.
  const char* wbase = (const char*)Wt + (size_t)octile * 16384 + tid * 16;

  auto stage = [&](int t) {
    const char* asrc = wbase + (size_t)t * 32768;
    #pragma unroll
    for (int i = 0; i < 4; ++i)
      gload16(asrc + i * 4096, &lds[tid * 8 + i * 2048]);
    int tap = t >> 1, ich = t & 1;
    int t3 = tap / 3;
    int dh = t3 - 1, dw = (tap - t3 * 3) - 1;
    bool ok = (unsigned)(sy + dh) < HW && (unsigned)(sx + dw) < HW;
    const char* bsrc = ok
        ? xtb + ((size_t)(sn * 16 + ich * 8) * NPIX + (sr + dh * HW + dw)) * 16
        : zpc;
    size_t step = ok ? (size_t)NPIX * 16 : 0;  // g+1 per k8
    #pragma unroll
    for (int i = 0; i < 8; ++i)
      gload16(bsrc + i * step, &lds[8192 + i * 2048 + tid * 8]);
  };

  f32x4 acc[4][8] = {};

  stage(0);
  WAITVM0; BARRIER;

  for (int t = 0; t < NKT; ++t) {
    #pragma unroll
    for (int kk = 0; kk < 2; ++kk) {
      f16x8 af[4], bf[8];
      #pragma unroll
      for (int q = 0; q < 4; ++q)
        af[q] = *(const f16x8*)
            &lds[((kk * 4 + lg) * 128 + wm * 64 + q * 16 + l15) * 8];
      #pragma unroll
      for (int q = 0; q < 8; ++q)
        bf[q] = *(const f16x8*)
            &lds[8192 + ((kk * 4 + lg) * 256 + wn * 128 + q * 16 + l15) * 8];
      __builtin_amdgcn_s_setprio(1);
      #pragma unroll
      for (int mq = 0; mq < 4; ++mq)
        #pragma unroll
        for (int nf = 0; nf < 8; ++nf)
          acc[mq][nf] = __builtin_amdgcn_mfma_f32_16x16x32_f16(
              af[mq], bf[nf], acc[mq][nf], 0, 0, 0);
      __builtin_amdgcn_s_setprio(0);
    }
    if (t + 1 < NKT) {
      BARRIER;                                // all waves done reading tile t
      stage(t + 1);
      WAITVM0; BARRIER;                       // tile t+1 in LDS
    }
  }

  // Epilogue. C/D: row(oc) = lg*4 + reg, col(pix) = l15.
  float* ob[8];
  #pragma unroll
  for (int nf = 0; nf < 8; ++nf) {
    int pp = ptile * 256 + wn * 128 + nf * 16 + l15;
    int nn = pp / NPIX, hw = pp % NPIX;
    ob[nf] = out + (size_t)nn * COUT * NPIX + hw;
  }
  #pragma unroll
  for (int mq = 0; mq < 4; ++mq) {
    int oc = octile * 128 + wm * 64 + mq * 16 + lg * 4;
    f32x4 bv = *(const f32x4*)&bias[oc];
    #pragma unroll
    for (int rr = 0; rr < 4; ++rr) {
      size_t row = (size_t)(oc + rr) * NPIX;
      #pragma unroll
      for (int nf = 0; nf < 8; ++nf)
        ob[nf][row] = acc[mq][nf][rr] + bv[rr];
    }
  }
}

// ---- fallback (only if ws too small): naive fp32 direct conv
__global__ void conv_naive(const float* __restrict__ x, const float* __restrict__ W,
                           const float* __restrict__ b, float* __restrict__ out) {
  int idx = blockIdx.x * 256 + threadIdx.x;
  int hw = idx % NPIX;
  int tmp = idx / NPIX;
  int oc = tmp % COUT;
  int n = tmp / COUT;
  int h = hw / HW, w = hw % HW;
  float acc = b[oc];
  for (int ic = 0; ic < CIN; ++ic) {
    const float* xr = x + (size_t)(n * CIN + ic) * NPIX;
    const float* wr = W + (size_t)(oc * CIN + ic) * 9;
    #pragma unroll
    for (int kh = 0; kh < 3; ++kh) {
      int ih = h + kh - 1;
      if ((unsigned)ih >= HW) continue;
      #pragma unroll
      for (int kw = 0; kw < 3; ++kw) {
        int iw = w + kw - 1;
        if ((unsigned)iw >= HW) continue;
        acc += xr[ih * HW + iw] * wr[kh * 3 + kw];
      }
    }
  }
  out[idx] = acc;
}

extern "C" void kernel_launch(void* const* d_in, const int* in_sizes, int n_in,
                              void* d_out, int out_size, void* d_ws, size_t ws_size,
                              hipStream_t stream) {
  const float* x = (const float*)d_in[0];
  const float* W = (const float*)d_in[1];
  const float* b = (const float*)d_in[2];
  float* out = (float*)d_out;

  const size_t ZP_OFF = 0;                    // 256 B zero page
  const size_t WT_OFF = 256;                  // 294912 * 2 = 589824 B
  const size_t XT_OFF = 256 + 589824;
  const size_t NEED = XT_OFF + (size_t)TOTPIX * CIN * 2;  // ~26.3 MB

  if (ws_size < NEED) {
    conv_naive<<<TOTPIX * COUT / 256, 256, 0, stream>>>(x, W, b, out);
    return;
  }
  char* ws = (char*)d_ws;
  u16* zp = (u16*)(ws + ZP_OFF);
  u16* Wt = (u16*)(ws + WT_OFF);
  u16* xt = (u16*)(ws + XT_OFF);

  prep<<<3200, 256, 0, stream>>>(x, W, xt, Wt, zp);
  conv_mfma<<<784, 256, 0, stream>>>(Wt, xt, b, out, zp);
}

// Round 22
// 89.452 us; speedup vs baseline: 3.4027x; 3.4027x over previous
//
#include <hip/hip_runtime.h>

// MyConv2D: N=32, Cin=128, H=W=56, Cout=256, K=3, stride=1, pad=1, fp32.
// R22 == R21 with the register-cap arithmetic FIXED. R21 spilled because
// launch_bounds(256,3) caps at 512/3=170 regs/thread (per-SIMD pool is 512,
// not 2048/3 — my error); demand ~210. launch_bounds(256,2) -> cap 256,
// fits. Geometry unchanged: 64x128 wave tile (acc=128), 128(oc)x256(pix)
// tile, 4 waves, BK=64, 18 K-tiles, 48KB single-buffer LDS, 2-barrier loop.
// 8 waves/CU (= R8's measured-good occupancy) with 25% less LDS traffic.

typedef unsigned short u16;
typedef _Float16 f16x8 __attribute__((ext_vector_type(8)));
typedef float f32x4 __attribute__((ext_vector_type(4)));

#define CIN    128
#define COUT   256
#define HW     56
#define NPIX   3136        // 56*56
#define TOTPIX 100352      // 32*3136
#define NKT    18          // K-tiles of 64 ic: 9 taps * 2 ic-halves

#define WAITVM0 asm volatile("s_waitcnt vmcnt(0)" ::: "memory")
#define BARRIER asm volatile("s_barrier" ::: "memory")

__device__ __forceinline__ void gload16(const void* g, void* l) {
  __builtin_amdgcn_global_load_lds(
      (const __attribute__((address_space(1))) void*)g,
      (__attribute__((address_space(3))) void*)l, 16, 0, 0);
}

__device__ __forceinline__ u16 f2h(float f) {
  _Float16 h = (_Float16)f;
  return __builtin_bit_cast(u16, h);
}

// ---- fused prep (unchanged from R20): blocks 0..2047 = x -> xt
// [n][g=ic/8][pix][8ic]; blocks 2048..3199 = W -> Wt [t][octile][k8][ocl]
// granules (+ zero-page init).
__global__ void prep(const float* __restrict__ x, const float* __restrict__ W,
                     u16* __restrict__ xt, u16* __restrict__ Wt,
                     u16* __restrict__ zp) {
  int b = blockIdx.x;
  if (b < 2048) {                             // ---- prep_x part
    int n = b >> 6, g = (b >> 2) & 15, c = b & 3;
    const float* xs = x + ((size_t)(n * 16 + g) * 8) * NPIX;
    u16* xd = xt + ((size_t)(n * 16 + g) * NPIX) * 8;
    #pragma unroll
    for (int i = 0; i < 4; ++i) {
      int off = i * 256 + (int)threadIdx.x;   // 784 = 3*256 + 16
      if (off < 784) {
        int pix = c * 784 + off;
        unsigned q0, q1, q2, q3;
        q0 = (unsigned)f2h(xs[(size_t)0 * NPIX + pix]) |
             ((unsigned)f2h(xs[(size_t)1 * NPIX + pix]) << 16);
        q1 = (unsigned)f2h(xs[(size_t)2 * NPIX + pix]) |
             ((unsigned)f2h(xs[(size_t)3 * NPIX + pix]) << 16);
        q2 = (unsigned)f2h(xs[(size_t)4 * NPIX + pix]) |
             ((unsigned)f2h(xs[(size_t)5 * NPIX + pix]) << 16);
        q3 = (unsigned)f2h(xs[(size_t)6 * NPIX + pix]) |
             ((unsigned)f2h(xs[(size_t)7 * NPIX + pix]) << 16);
        uint4 v; v.x = q0; v.y = q1; v.z = q2; v.w = q3;
        *(uint4*)(xd + (size_t)pix * 8) = v;
      }
    }
  } else {                                    // ---- prep_w part
    int e = (b - 2048) * 256 + threadIdx.x;   // 1152 * 256 = 294912
    if (b == 2048 && threadIdx.x < 128) zp[threadIdx.x] = 0;
    int j   = e & 7;
    int ocl = (e >> 3) & 127;
    int k8  = (e >> 10) & 7;
    int o   = (e >> 13) & 1;
    int t   = e >> 14;                        // 0..17
    int oc = o * 128 + ocl;
    int ic = (t & 1) * 64 + k8 * 8 + j;
    Wt[e] = f2h(W[(oc * CIN + ic) * 9 + (t >> 1)]);
  }
}

__global__ __launch_bounds__(256, 2) void conv_mfma(
    const u16* __restrict__ Wt, const u16* __restrict__ xt,
    const float* __restrict__ bias, float* __restrict__ out,
    const u16* __restrict__ zp) {
  // 48KB: A [k8 8][ocl 128][8] at 0 (16KB) | B [k8 8][pixl 256][8] at 8192.
  __shared__ __align__(16) u16 lds[24576];

  int tid  = threadIdx.x;                     // 0..255
  int lane = tid & 63;
  int wv   = tid >> 6;                        // 0..3
  int bid  = blockIdx.x;                      // 0..783
  int wgid = (bid & 7) * 98 + (bid >> 3);     // XCD swizzle (784 = 8*98)
  int octile = wgid & 1;                      // same-XCD pair shares B panel
  int ptile  = wgid >> 1;                     // 0..391

  int wm = wv >> 1, wn = wv & 1;              // per-wave 64(oc) x 128(pix)
  int l15 = lane & 15, lg = lane >> 4;

  // B staging: thread owns pixel spix = tid, stages all 8 k8 granules.
  int spix = tid;
  int p = ptile * 256 + spix;
  int sn = p / NPIX, sr = p % NPIX, sy = sr / HW, sx = sr % HW;
  const char* xtb = (const char*)xt;
  const char* zpc = (const char*)zp;
  // A staging: granules linear, 4/thread: (k8*128+ocl) = tid + i*256.
  const char* wbase = (const char*)Wt + (size_t)octile * 16384 + tid * 16;

  auto stage = [&](int t) {
    const char* asrc = wbase + (size_t)t * 32768;
    #pragma unroll
    for (int i = 0; i < 4; ++i)
      gload16(asrc + i * 4096, &lds[tid * 8 + i * 2048]);
    int tap = t >> 1, ich = t & 1;
    int t3 = tap / 3;
    int dh = t3 - 1, dw = (tap - t3 * 3) - 1;
    bool ok = (unsigned)(sy + dh) < HW && (unsigned)(sx + dw) < HW;
    const char* bsrc = ok
        ? xtb + ((size_t)(sn * 16 + ich * 8) * NPIX + (sr + dh * HW + dw)) * 16
        : zpc;
    size_t step = ok ? (size_t)NPIX * 16 : 0;  // g+1 per k8
    #pragma unroll
    for (int i = 0; i < 8; ++i)
      gload16(bsrc + i * step, &lds[8192 + i * 2048 + tid * 8]);
  };

  f32x4 acc[4][8] = {};

  stage(0);
  WAITVM0; BARRIER;

  for (int t = 0; t < NKT; ++t) {
    #pragma unroll
    for (int kk = 0; kk < 2; ++kk) {
      f16x8 af[4], bf[8];
      #pragma unroll
      for (int q = 0; q < 4; ++q)
        af[q] = *(const f16x8*)
            &lds[((kk * 4 + lg) * 128 + wm * 64 + q * 16 + l15) * 8];
      #pragma unroll
      for (int q = 0; q < 8; ++q)
        bf[q] = *(const f16x8*)
            &lds[8192 + ((kk * 4 + lg) * 256 + wn * 128 + q * 16 + l15) * 8];
      __builtin_amdgcn_s_setprio(1);
      #pragma unroll
      for (int mq = 0; mq < 4; ++mq)
        #pragma unroll
        for (int nf = 0; nf < 8; ++nf)
          acc[mq][nf] = __builtin_amdgcn_mfma_f32_16x16x32_f16(
              af[mq], bf[nf], acc[mq][nf], 0, 0, 0);
      __builtin_amdgcn_s_setprio(0);
    }
    if (t + 1 < NKT) {
      BARRIER;                                // all waves done reading tile t
      stage(t + 1);
      WAITVM0; BARRIER;                       // tile t+1 in LDS
    }
  }

  // Epilogue. C/D: row(oc) = lg*4 + reg, col(pix) = l15.
  float* ob[8];
  #pragma unroll
  for (int nf = 0; nf < 8; ++nf) {
    int pp = ptile * 256 + wn * 128 + nf * 16 + l15;
    int nn = pp / NPIX, hw = pp % NPIX;
    ob[nf] = out + (size_t)nn * COUT * NPIX + hw;
  }
  #pragma unroll
  for (int mq = 0; mq < 4; ++mq) {
    int oc = octile * 128 + wm * 64 + mq * 16 + lg * 4;
    f32x4 bv = *(const f32x4*)&bias[oc];
    #pragma unroll
    for (int rr = 0; rr < 4; ++rr) {
      size_t row = (size_t)(oc + rr) * NPIX;
      #pragma unroll
      for (int nf = 0; nf < 8; ++nf)
        ob[nf][row] = acc[mq][nf][rr] + bv[rr];
    }
  }
}

// ---- fallback (only if ws too small): naive fp32 direct conv
__global__ void conv_naive(const float* __restrict__ x, const float* __restrict__ W,
                           const float* __restrict__ b, float* __restrict__ out) {
  int idx = blockIdx.x * 256 + threadIdx.x;
  int hw = idx % NPIX;
  int tmp = idx / NPIX;
  int oc = tmp % COUT;
  int n = tmp / COUT;
  int h = hw / HW, w = hw % HW;
  float acc = b[oc];
  for (int ic = 0; ic < CIN; ++ic) {
    const float* xr = x + (size_t)(n * CIN + ic) * NPIX;
    const float* wr = W + (size_t)(oc * CIN + ic) * 9;
    #pragma unroll
    for (int kh = 0; kh < 3; ++kh) {
      int ih = h + kh - 1;
      if ((unsigned)ih >= HW) continue;
      #pragma unroll
      for (int kw = 0; kw < 3; ++kw) {
        int iw = w + kw - 1;
        if ((unsigned)iw >= HW) continue;
        acc += xr[ih * HW + iw] * wr[kh * 3 + kw];
      }
    }
  }
  out[idx] = acc;
}

extern "C" void kernel_launch(void* const* d_in, const int* in_sizes, int n_in,
                              void* d_out, int out_size, void* d_ws, size_t ws_size,
                              hipStream_t stream) {
  const float* x = (const float*)d_in[0];
  const float* W = (const float*)d_in[1];
  const float* b = (const float*)d_in[2];
  float* out = (float*)d_out;

  const size_t ZP_OFF = 0;                    // 256 B zero page
  const size_t WT_OFF = 256;                  // 294912 * 2 = 589824 B
  const size_t XT_OFF = 256 + 589824;
  const size_t NEED = XT_OFF + (size_t)TOTPIX * CIN * 2;  // ~26.3 MB

  if (ws_size < NEED) {
    conv_naive<<<TOTPIX * COUT / 256, 256, 0, stream>>>(x, W, b, out);
    return;
  }
  char* ws = (char*)d_ws;
  u16* zp = (u16*)(ws + ZP_OFF);
  u16* Wt = (u16*)(ws + WT_OFF);
  u16* xt = (u16*)(ws + XT_OFF);

  prep<<<3200, 256, 0, stream>>>(x, W, xt, Wt, zp);
  conv_mfma<<<784, 256, 0, stream>>>(Wt, xt, b, out, zp);
}

// Round 23
// 85.880 us; speedup vs baseline: 3.5443x; 1.0416x over previous
//
#include <hip/hip_runtime.h>

// MyConv2D: N=32, Cin=128, H=W=56, Cout=256, K=3, stride=1, pad=1, fp32.
// FINAL (== R20, best measured: 86.2us total / ~74us conv, stable).
// Implicit-GEMM fp16 MFMA 16x16x32, 128(oc)x128(pix) tile, 4 waves,
// per-wave 64x64 (acc=64), BK=64, 18 K-tiles, 32KB single-buffer
// conflict-free LDS, global_load_lds width-16, zero-page border taps,
// XCD swizzle, fused LDS-free prep (x->xt transpose || W->Wt pack).
// Plateau (R1-R22, all axes measured): balanced MFMA ~26us / LDS ~40us /
// staging pipes; schedule, occupancy, granularity, wave-aspect, B-bypass,
// MFMA-shape variants all within +-3% or worse. This is the optimum found.

typedef unsigned short u16;
typedef _Float16 f16x8 __attribute__((ext_vector_type(8)));
typedef float f32x4 __attribute__((ext_vector_type(4)));

#define CIN    128
#define COUT   256
#define HW     56
#define NPIX   3136        // 56*56
#define TOTPIX 100352      // 32*3136
#define NKT    18          // K-tiles of 64 ic: 9 taps * 2 ic-halves

#define WAITVM0 asm volatile("s_waitcnt vmcnt(0)" ::: "memory")
#define BARRIER asm volatile("s_barrier" ::: "memory")

__device__ __forceinline__ void gload16(const void* g, void* l) {
  __builtin_amdgcn_global_load_lds(
      (const __attribute__((address_space(1))) void*)g,
      (__attribute__((address_space(3))) void*)l, 16, 0, 0);
}

__device__ __forceinline__ u16 f2h(float f) {
  _Float16 h = (_Float16)f;
  return __builtin_bit_cast(u16, h);
}

// ---- fused prep: blocks 0..2047 transpose x -> xt [n][g=ic/8][pix][8ic];
// blocks 2048..3199 pack W -> Wt [t 18][octile 2][k8 8][ocl 128] granules
// (+ zero-page init).
__global__ void prep(const float* __restrict__ x, const float* __restrict__ W,
                     u16* __restrict__ xt, u16* __restrict__ Wt,
                     u16* __restrict__ zp) {
  int b = blockIdx.x;
  if (b < 2048) {                             // ---- prep_x part
    int n = b >> 6, g = (b >> 2) & 15, c = b & 3;
    const float* xs = x + ((size_t)(n * 16 + g) * 8) * NPIX;
    u16* xd = xt + ((size_t)(n * 16 + g) * NPIX) * 8;
    #pragma unroll
    for (int i = 0; i < 4; ++i) {
      int off = i * 256 + (int)threadIdx.x;   // 784 = 3*256 + 16
      if (off < 784) {
        int pix = c * 784 + off;
        unsigned q0, q1, q2, q3;
        q0 = (unsigned)f2h(xs[(size_t)0 * NPIX + pix]) |
             ((unsigned)f2h(xs[(size_t)1 * NPIX + pix]) << 16);
        q1 = (unsigned)f2h(xs[(size_t)2 * NPIX + pix]) |
             ((unsigned)f2h(xs[(size_t)3 * NPIX + pix]) << 16);
        q2 = (unsigned)f2h(xs[(size_t)4 * NPIX + pix]) |
             ((unsigned)f2h(xs[(size_t)5 * NPIX + pix]) << 16);
        q3 = (unsigned)f2h(xs[(size_t)6 * NPIX + pix]) |
             ((unsigned)f2h(xs[(size_t)7 * NPIX + pix]) << 16);
        uint4 v; v.x = q0; v.y = q1; v.z = q2; v.w = q3;
        *(uint4*)(xd + (size_t)pix * 8) = v;
      }
    }
  } else {                                    // ---- prep_w part
    int e = (b - 2048) * 256 + threadIdx.x;   // 1152 * 256 = 294912
    if (b == 2048 && threadIdx.x < 128) zp[threadIdx.x] = 0;
    int j   = e & 7;
    int ocl = (e >> 3) & 127;
    int k8  = (e >> 10) & 7;
    int o   = (e >> 13) & 1;
    int t   = e >> 14;                        // 0..17
    int oc = o * 128 + ocl;
    int ic = (t & 1) * 64 + k8 * 8 + j;
    Wt[e] = f2h(W[(oc * CIN + ic) * 9 + (t >> 1)]);
  }
}

__global__ __launch_bounds__(256, 4) void conv_mfma(
    const u16* __restrict__ Wt, const u16* __restrict__ xt,
    const float* __restrict__ bias, float* __restrict__ out,
    const u16* __restrict__ zp) {
  // 32KB single buffer: A [k8 8][ocl 128][8] at 0 | B [k8 8][pixl 128][8] at 8192.
  __shared__ __align__(16) u16 lds[16384];

  int tid  = threadIdx.x;                     // 0..255
  int lane = tid & 63;
  int wv   = tid >> 6;                        // 0..3
  int bid  = blockIdx.x;                      // 0..1567
  int wgid = (bid & 7) * 196 + (bid >> 3);    // XCD swizzle (1568 = 8*196)
  int octile = wgid & 1;                      // same-XCD pair shares B panel
  int ptile  = wgid >> 1;                     // 0..783

  int wm = wv >> 1, wn = wv & 1;              // 2M x 2N waves, per-wave 64x64
  int l15 = lane & 15, lg = lane >> 4;

  // B staging: thread owns pixel spix = tid&127, g = (tid>>7) + 2i (i=0..3).
  int spix = tid & 127;
  int p = ptile * 128 + spix;
  int sn = p / NPIX, sr = p % NPIX, sy = sr / HW, sx = sr % HW;
  const char* xtb = (const char*)xt;
  const char* zpc = (const char*)zp;
  // A staging: granules linear, 4/thread: (k8*128+ocl) = tid + i*256.
  const char* wbase = (const char*)Wt + (size_t)octile * 16384 + tid * 16;

  auto stage = [&](int t) {
    const char* asrc = wbase + (size_t)t * 32768;
    #pragma unroll
    for (int i = 0; i < 4; ++i)
      gload16(asrc + i * 4096, &lds[tid * 8 + i * 2048]);
    int tap = t >> 1, ich = t & 1;
    int t3 = tap / 3;
    int dh = t3 - 1, dw = (tap - t3 * 3) - 1;
    bool ok = (unsigned)(sy + dh) < HW && (unsigned)(sx + dw) < HW;
    const char* bsrc = ok
        ? xtb + ((size_t)(sn * 16 + ich * 8 + (tid >> 7)) * NPIX +
                 (sr + dh * HW + dw)) * 16
        : zpc;
    size_t step = ok ? (size_t)2 * NPIX * 16 : 0;
    u16* bdst = &lds[8192 + ((tid >> 7) * 128 + spix) * 8];
    #pragma unroll
    for (int i = 0; i < 4; ++i)
      gload16(bsrc + i * step, bdst + i * 2048);  // g+2 -> +2*128 granules
  };

  f32x4 acc[4][4] = {};

  stage(0);
  WAITVM0; BARRIER;

  for (int t = 0; t < NKT; ++t) {
    #pragma unroll
    for (int kk = 0; kk < 2; ++kk) {
      f16x8 af[4], bf[4];
      #pragma unroll
      for (int q = 0; q < 4; ++q)
        af[q] = *(const f16x8*)
            &lds[((kk * 4 + lg) * 128 + wm * 64 + q * 16 + l15) * 8];
      #pragma unroll
      for (int q = 0; q < 4; ++q)
        bf[q] = *(const f16x8*)
            &lds[8192 + ((kk * 4 + lg) * 128 + wn * 64 + q * 16 + l15) * 8];
      __builtin_amdgcn_s_setprio(1);
      #pragma unroll
      for (int mq = 0; mq < 4; ++mq)
        #pragma unroll
        for (int nf = 0; nf < 4; ++nf)
          acc[mq][nf] = __builtin_amdgcn_mfma_f32_16x16x32_f16(
              af[mq], bf[nf], acc[mq][nf], 0, 0, 0);
      __builtin_amdgcn_s_setprio(0);
    }
    if (t + 1 < NKT) {
      BARRIER;                                // all waves done reading tile t
      stage(t + 1);
      WAITVM0; BARRIER;                       // tile t+1 in LDS
    }
  }

  // Epilogue. C/D: row(oc) = lg*4 + reg, col(pix) = l15.
  float* ob[4];
  #pragma unroll
  for (int nf = 0; nf < 4; ++nf) {
    int pp = ptile * 128 + wn * 64 + nf * 16 + l15;
    int nn = pp / NPIX, hw = pp % NPIX;
    ob[nf] = out + (size_t)nn * COUT * NPIX + hw;
  }
  #pragma unroll
  for (int mq = 0; mq < 4; ++mq) {
    int oc = octile * 128 + wm * 64 + mq * 16 + lg * 4;
    f32x4 bv = *(const f32x4*)&bias[oc];
    #pragma unroll
    for (int rr = 0; rr < 4; ++rr) {
      size_t row = (size_t)(oc + rr) * NPIX;
      #pragma unroll
      for (int nf = 0; nf < 4; ++nf)
        ob[nf][row] = acc[mq][nf][rr] + bv[rr];
    }
  }
}

// ---- fallback (only if ws too small): naive fp32 direct conv
__global__ void conv_naive(const float* __restrict__ x, const float* __restrict__ W,
                           const float* __restrict__ b, float* __restrict__ out) {
  int idx = blockIdx.x * 256 + threadIdx.x;
  int hw = idx % NPIX;
  int tmp = idx / NPIX;
  int oc = tmp % COUT;
  int n = tmp / COUT;
  int h = hw / HW, w = hw % HW;
  float acc = b[oc];
  for (int ic = 0; ic < CIN; ++ic) {
    const float* xr = x + (size_t)(n * CIN + ic) * NPIX;
    const float* wr = W + (size_t)(oc * CIN + ic) * 9;
    #pragma unroll
    for (int kh = 0; kh < 3; ++kh) {
      int ih = h + kh - 1;
      if ((unsigned)ih >= HW) continue;
      #pragma unroll
      for (int kw = 0; kw < 3; ++kw) {
        int iw = w + kw - 1;
        if ((unsigned)iw >= HW) continue;
        acc += xr[ih * HW + iw] * wr[kh * 3 + kw];
      }
    }
  }
  out[idx] = acc;
}

extern "C" void kernel_launch(void* const* d_in, const int* in_sizes, int n_in,
                              void* d_out, int out_size, void* d_ws, size_t ws_size,
                              hipStream_t stream) {
  const float* x = (const float*)d_in[0];
  const float* W = (const float*)d_in[1];
  const float* b = (const float*)d_in[2];
  float* out = (float*)d_out;

  const size_t ZP_OFF = 0;                    // 256 B zero page
  const size_t WT_OFF = 256;                  // 294912 * 2 = 589824 B
  const size_t XT_OFF = 256 + 589824;
  const size_t NEED = XT_OFF + (size_t)TOTPIX * CIN * 2;  // ~26.3 MB

  if (ws_size < NEED) {
    conv_naive<<<TOTPIX * COUT / 256, 256, 0, stream>>>(x, W, b, out);
    return;
  }
  char* ws = (char*)d_ws;
  u16* zp = (u16*)(ws + ZP_OFF);
  u16* Wt = (u16*)(ws + WT_OFF);
  u16* xt = (u16*)(ws + XT_OFF);

  prep<<<3200, 256, 0, stream>>>(x, W, xt, Wt, zp);
  conv_mfma<<<1568, 256, 0, stream>>>(Wt, xt, b, out, zp);
}